// Round 18
// baseline (241.662 us; speedup 1.0000x reference)
//
#include <hip/hip_runtime.h>
#include <hip/hip_bf16.h>
#include <math.h>

#define N_NODES 50000
#define N_EDGES 800000
#define F_IN    128
#define HID     64
#define HEADS   4
#define NCLS    16
#define NEG_SLOPE 0.2f

typedef __attribute__((ext_vector_type(8))) _Float16 half8v;
typedef __attribute__((ext_vector_type(4))) float f32x4;
typedef __attribute__((ext_vector_type(2))) float f32x2;

static __device__ __forceinline__ float lrelu(float x) {
    return x >= 0.f ? x : NEG_SLOPE * x;
}
static __device__ __forceinline__ unsigned short f2h(float f) {
    _Float16 h = (_Float16)f;
    return __builtin_bit_cast(unsigned short, h);
}
static __device__ __forceinline__ float h2f(unsigned short u) {
    return (float)__builtin_bit_cast(_Float16, u);
}

// ---------------- zero counts ----------------
__global__ void k_zero(int4* __restrict__ p, int n4) {
    int i = blockIdx.x * blockDim.x + threadIdx.x;
    if (i < n4) p[i] = int4{0, 0, 0, 0};
}

// ---------------- fused prep: W1t, W2t, W3ht, edge histogram + ranks ----------------
#define NB_WT1  128           // 128*256 / 256
#define NB_WT2  256           // 256*256 / 256
#define NB_WT3  16            // 256*16 / 256
#define NB_HIST 3125          // E / 256
__global__ void k_prep(const float* __restrict__ W1, unsigned short* __restrict__ W1t,
                       const float* __restrict__ W2, unsigned short* __restrict__ W2t,
                       const float* __restrict__ W3, unsigned short* __restrict__ W3ht,
                       const int* __restrict__ dst, int* __restrict__ counts,
                       unsigned short* __restrict__ rank) {
    int bid = blockIdx.x, tid = threadIdx.x;
    if (bid < NB_WT1) {
        int i = bid * 256 + tid;
        int k = i >> 8, c = i & 255;
        W1t[c * F_IN + k] = f2h(W1[i]);
    } else if (bid < NB_WT1 + NB_WT2) {
        int i = (bid - NB_WT1) * 256 + tid;
        int k = i >> 8, c = i & 255;
        W2t[c * 256 + k] = f2h(W2[i]);
    } else if (bid < NB_WT1 + NB_WT2 + NB_WT3) {
        int i = (bid - NB_WT1 - NB_WT2) * 256 + tid;
        int k = i >> 4, c = i & 15;        // W3 is [256][16]
        W3ht[c * 256 + k] = f2h(W3[i]);
    } else {
        int i = (bid - NB_WT1 - NB_WT2 - NB_WT3) * 256 + tid;
        if (i < N_EDGES) rank[i] = (unsigned short)atomicAdd(&counts[dst[i]], 1);
    }
}

// ---------------- CSR scan ----------------
__global__ __launch_bounds__(256) void k_scan1(const int* __restrict__ counts, int* __restrict__ incl,
                                               int* __restrict__ bsums, int n) {
    __shared__ int wsum[4];
    int blk = blockIdx.x, tid = threadIdx.x;
    int lane = tid & 63, w = tid >> 6;
    int i0 = blk * 1024 + tid * 4;
    int v[4];
    #pragma unroll
    for (int j = 0; j < 4; j++) v[j] = (i0 + j < n) ? counts[i0 + j] : 0;
    int t = v[0] + v[1] + v[2] + v[3];
    int x = t;
    #pragma unroll
    for (int d = 1; d < 64; d <<= 1) { int y = __shfl_up(x, d); if (lane >= d) x += y; }
    if (lane == 63) wsum[w] = x;
    __syncthreads();
    int woff = 0;
    #pragma unroll
    for (int ww = 0; ww < 4; ww++) woff += (ww < w) ? wsum[ww] : 0;
    int p = woff + x - t;
    #pragma unroll
    for (int j = 0; j < 4; j++) { p += v[j]; if (i0 + j < n) incl[i0 + j] = p; }
    if (tid == 255) bsums[blk] = woff + x;
}

__global__ void k_scan2(const int* __restrict__ bsums, int* __restrict__ boffs, int nb, int* rowptr_end) {
    int lane = threadIdx.x;
    int v = (lane < nb) ? bsums[lane] : 0;
    int x = v;
    #pragma unroll
    for (int d = 1; d < 64; d <<= 1) { int y = __shfl_up(x, d); if (lane >= d) x += y; }
    if (lane < nb) boffs[lane] = x - v;
    if (lane == 63) *rowptr_end = x;
}

__global__ void k_scan3(const int* __restrict__ incl, const int* __restrict__ counts,
                        const int* __restrict__ boffs, int* __restrict__ rowptr, int n) {
    int i = blockIdx.x * blockDim.x + threadIdx.x;
    if (i < n) rowptr[i] = boffs[i >> 10] + incl[i] - counts[i];
}

// ---------------- swizzle for MFMA LDS tiles ----------------
static __device__ __forceinline__ int swz(int r, int lc) {
    return r * 4 + (lc ^ (r & 3) ^ ((r >> 2) & 1));
}

// ---------------- GEMM body (f16 MFMA, 128x256, 4 waves) + fused scores ----------
template<int CONVA>
static __device__ __forceinline__ void gemm_body(
        int bid, const void* __restrict__ Av, const unsigned short* __restrict__ Bt,
        const float* __restrict__ asrc, const float* __restrict__ adst,
        unsigned char* __restrict__ C8, float* __restrict__ s_src, float* __restrict__ s_dst,
        int M, int K, unsigned short* Asm, unsigned short* Bsm) {
    int tid = threadIdx.x;
    int lane = tid & 63, wid = tid >> 6;
    int bx = bid & 1, by = bid >> 1;
    int row0 = by * 128, col0 = bx * 128;
    int wr = wid >> 1, wc = wid & 1;
    f32x4 acc[4][4] = {};

    for (int k0 = 0; k0 < K; k0 += 32) {
        __syncthreads();
        #pragma unroll
        for (int s = 0; s < 2; s++) {
            int c = tid + s * 256;
            int row = c >> 2, lc = c & 3;
            int gr = row0 + row; if (gr >= M) gr = 0;
            uint4 va;
            if (CONVA) {
                const float* Af = (const float*)Av + (size_t)gr * K + k0 + lc * 8;
                float4 fa = *(const float4*)Af;
                float4 fb = *(const float4*)(Af + 4);
                va.x = (unsigned)f2h(fa.x) | ((unsigned)f2h(fa.y) << 16);
                va.y = (unsigned)f2h(fa.z) | ((unsigned)f2h(fa.w) << 16);
                va.z = (unsigned)f2h(fb.x) | ((unsigned)f2h(fb.y) << 16);
                va.w = (unsigned)f2h(fb.z) | ((unsigned)f2h(fb.w) << 16);
            } else {
                va = *(const uint4*)((const unsigned short*)Av + (size_t)gr * K + k0 + lc * 8);
            }
            *(uint4*)(&Asm[swz(row, lc) * 8]) = va;
            uint4 vb = *(const uint4*)(Bt + (size_t)(col0 + row) * K + k0 + lc * 8);
            *(uint4*)(&Bsm[swz(row, lc) * 8]) = vb;
        }
        __syncthreads();
        half8v af[4], bg[4];
        int lq = lane >> 4;
        #pragma unroll
        for (int m = 0; m < 4; m++) {
            int r = wr * 64 + m * 16 + (lane & 15);
            af[m] = *(const half8v*)(&Asm[swz(r, lq) * 8]);
        }
        #pragma unroll
        for (int n = 0; n < 4; n++) {
            int r = wc * 64 + n * 16 + (lane & 15);
            bg[n] = *(const half8v*)(&Bsm[swz(r, lq) * 8]);
        }
        #pragma unroll
        for (int m = 0; m < 4; m++)
            #pragma unroll
            for (int n = 0; n < 4; n++)
                acc[m][n] = __builtin_amdgcn_mfma_f32_16x16x32_f16(af[m], bg[n], acc[m][n], 0, 0, 0);
    }

    #pragma unroll
    for (int m = 0; m < 4; m++) {
        #pragma unroll
        for (int r = 0; r < 4; r++) {
            int row = row0 + wr * 64 + m * 16 + (lane >> 4) * 4 + r;
            if (row < M) {
                int q01 = __builtin_amdgcn_cvt_pk_fp8_f32(acc[m][0][r], acc[m][1][r], 0, false);
                int q23 = __builtin_amdgcn_cvt_pk_fp8_f32(acc[m][2][r], acc[m][3][r], 0, false);
                size_t base = (size_t)row * 256 + col0 + wc * 64 + (lane & 15);
                C8[base]      = (unsigned char)(q01 & 0xff);
                C8[base + 16] = (unsigned char)((q01 >> 8) & 0xff);
                C8[base + 32] = (unsigned char)(q23 & 0xff);
                C8[base + 48] = (unsigned char)((q23 >> 8) & 0xff);
            }
        }
    }

    int c16 = lane & 15, lq = lane >> 4;
    int head = bx * 2 + wc;
    float avs[4], avd[4];
    #pragma unroll
    for (int nn = 0; nn < 4; nn++) {
        avs[nn] = asrc[head * 64 + nn * 16 + c16];
        avd[nn] = adst[head * 64 + nn * 16 + c16];
    }
    #pragma unroll
    for (int mm = 0; mm < 4; mm++) {
        #pragma unroll
        for (int r = 0; r < 4; r++) {
            float ps = 0.f, pd = 0.f;
            #pragma unroll
            for (int nn = 0; nn < 4; nn++) {
                ps += acc[mm][nn][r] * avs[nn];
                pd += acc[mm][nn][r] * avd[nn];
            }
            #pragma unroll
            for (int off = 1; off < 16; off <<= 1) {
                ps += __shfl_xor(ps, off);
                pd += __shfl_xor(pd, off);
            }
            if (c16 == 0) {
                int grow = row0 + wr * 64 + mm * 16 + lq * 4 + r;
                if (grow < M) {
                    s_src[grow * 4 + head] = ps;
                    s_dst[grow * 4 + head] = pd;
                }
            }
        }
    }
}

// fused: layer-1 GEMM (f32 A, fp8 C) + atomic-free CSR scatter (ushort col)
__global__ __launch_bounds__(256) void k_b(const float* __restrict__ A,
                                           const unsigned short* __restrict__ Bt,
                                           const float* __restrict__ asrc,
                                           const float* __restrict__ adst,
                                           unsigned char* __restrict__ C8,
                                           float* __restrict__ s_src,
                                           float* __restrict__ s_dst,
                                           int M, int K, int gemmBlocks,
                                           const int* __restrict__ src, const int* __restrict__ dst,
                                           const int* __restrict__ rowptr,
                                           const unsigned short* __restrict__ rank,
                                           unsigned short* __restrict__ col, int e) {
    __shared__ unsigned short Asm[128 * 32];
    __shared__ unsigned short Bsm[128 * 32];
    int bid = blockIdx.x;
    if (bid < gemmBlocks) {
        gemm_body<1>(bid, A, Bt, asrc, adst, C8, s_src, s_dst, M, K, Asm, Bsm);
    } else {
        int half = (e + 1) >> 1;
        int i = (bid - gemmBlocks) * 256 + (int)threadIdx.x;
        if (i < half) {
            int d = dst[i];
            col[rowptr[d] + rank[i]] = (unsigned short)src[i];
        }
        int j = i + half;
        if (j < e) {
            int d = dst[j];
            col[rowptr[d] + rank[j]] = (unsigned short)src[j];
        }
    }
}

// ---------------- per-edge accumulate macros (fp8 h, pk_fma) ----------------
#define PEDGE(SV, SD) __expf(fminf(lrelu((SV) + (SD)), 80.f))
#define ACC8(P, HV) { \
    f32x2 pbc = {(P), (P)}; \
    f32x2 v0 = __builtin_amdgcn_cvt_pk_f32_fp8((HV).x, false); \
    f32x2 v1 = __builtin_amdgcn_cvt_pk_f32_fp8((HV).x, true);  \
    f32x2 v2 = __builtin_amdgcn_cvt_pk_f32_fp8((HV).y, false); \
    f32x2 v3 = __builtin_amdgcn_cvt_pk_f32_fp8((HV).y, true);  \
    asm("v_pk_fma_f32 %0, %1, %2, %0" : "+v"(a01) : "v"(v0), "v"(pbc)); \
    asm("v_pk_fma_f32 %0, %1, %2, %0" : "+v"(a23) : "v"(v1), "v"(pbc)); \
    asm("v_pk_fma_f32 %0, %1, %2, %0" : "+v"(a45) : "v"(v2), "v"(pbc)); \
    asm("v_pk_fma_f32 %0, %1, %2, %0" : "+v"(a67) : "v"(v3), "v"(pbc)); \
    z += (P); }

// aggregation core: returns packed f16 ov for this half's node (zeros if node>=n)
static __device__ __forceinline__ uint4 agg_core(
        int node, int n, int head, int j8, int base8, unsigned foff,
        const unsigned char* __restrict__ h8, const int* __restrict__ rowptr,
        const unsigned short* __restrict__ col,
        const float* __restrict__ s_src, const float* __restrict__ s_dst,
        const float* __restrict__ bias, int l5) {
    uint4 ov = {0, 0, 0, 0};
    if (node >= n) return ov;
    int rs = rowptr[node], re = rowptr[node + 1];
    float sd = s_dst[node * 4 + head];
    float z = 0.f;
    f32x2 a01 = {0.f, 0.f}, a23 = {0.f, 0.f}, a45 = {0.f, 0.f}, a67 = {0.f, 0.f};
    {
        float pself = PEDGE(s_src[node * 4 + head], sd);
        uint2 own = *(const uint2*)(h8 + (((unsigned)node << 8) + foff));
        ACC8(pself, own);
    }
    int i = rs;
    for (; i + 7 < re; i += 8) {
        unsigned cc[8];
        #pragma unroll
        for (int j = 0; j < 8; j++) cc[j] = col[i + j];
        float s_own = s_src[cc[j8] * 4 + head];
        uint2 hv[8];
        #pragma unroll
        for (int j = 0; j < 8; j++)
            hv[j] = *(const uint2*)(h8 + ((cc[j] << 8) + foff));
        float p_own = PEDGE(s_own, sd);
        float pv[8];
        #pragma unroll
        for (int j = 0; j < 8; j++) pv[j] = __shfl(p_own, base8 + j);
        #pragma unroll
        for (int j = 0; j < 8; j++) { ACC8(pv[j], hv[j]); }
    }
    for (; i + 3 < re; i += 4) {
        unsigned cc[4];
        #pragma unroll
        for (int j = 0; j < 4; j++) cc[j] = col[i + j];
        float s_own = s_src[cc[j8 & 3] * 4 + head];
        uint2 hv[4];
        #pragma unroll
        for (int j = 0; j < 4; j++)
            hv[j] = *(const uint2*)(h8 + ((cc[j] << 8) + foff));
        float p_own = PEDGE(s_own, sd);
        float pv[4];
        #pragma unroll
        for (int j = 0; j < 4; j++) pv[j] = __shfl(p_own, base8 + j);
        #pragma unroll
        for (int j = 0; j < 4; j++) { ACC8(pv[j], hv[j]); }
    }
    for (; i < re; i++) {
        unsigned c0 = col[i];
        float s0 = s_src[c0 * 4 + head];
        uint2 h0 = *(const uint2*)(h8 + ((c0 << 8) + foff));
        float p0 = PEDGE(s0, sd);
        ACC8(p0, h0);
    }
    float inv = 1.f / z;
    int f0 = l5 * 8;
    float4 bv0 = *(const float4*)(bias + f0);
    float4 bv1 = *(const float4*)(bias + f0 + 4);
    float o[8];
    o[0] = a01.x * inv + bv0.x; o[1] = a01.y * inv + bv0.y;
    o[2] = a23.x * inv + bv0.z; o[3] = a23.y * inv + bv0.w;
    o[4] = a45.x * inv + bv1.x; o[5] = a45.y * inv + bv1.y;
    o[6] = a67.x * inv + bv1.z; o[7] = a67.y * inv + bv1.w;
    #pragma unroll
    for (int j = 0; j < 8; j++) o[j] = o[j] > 0.f ? o[j] : __expf(o[j]) - 1.f;
    unsigned* wd = (unsigned*)&ov;
    #pragma unroll
    for (int j = 0; j < 4; j++)
        wd[j] = (unsigned)f2h(o[2 * j]) | ((unsigned)f2h(o[2 * j + 1]) << 16);
    return ov;
}

// ---------------- fused: layer-1 aggregation (16 nodes -> LDS) + GEMM2 + scores2 ------
// 256 threads = 4 waves. Phase A: wave w aggregates nodes blk*16 + w*4 .. +3 (2 passes).
// Phase B: wave w computes head-w cols (w*64..w*64+63) of C2 = A @ W2 via 32 MFMA.
__global__ __launch_bounds__(256) void k_fuse2(
        const unsigned char* __restrict__ h8, const int* __restrict__ rowptr,
        const unsigned short* __restrict__ col,
        const float* __restrict__ s_src, const float* __restrict__ s_dst,
        const float* __restrict__ bias,
        const unsigned short* __restrict__ W2t,    // [256 cols][256 k] f16
        const float* __restrict__ a2s, const float* __restrict__ a2d,
        unsigned char* __restrict__ C8,
        float* __restrict__ s_src2, float* __restrict__ s_dst2, int n) {
    __shared__ unsigned short ALds[16 * 264];
    int tid = threadIdx.x;
    int lane = tid & 63, wv = tid >> 6;
    int half = lane >> 5, l5 = lane & 31;
    int head = l5 >> 3, j8 = l5 & 7, base8 = lane & ~7;
    unsigned foff = (unsigned)(l5 * 8);

    // phase A: aggregate 16 nodes into LDS A-tile
    #pragma unroll
    for (int p = 0; p < 2; p++) {
        int nl = wv * 4 + p * 2 + half;
        int node = blockIdx.x * 16 + nl;
        uint4 ov = agg_core(node, n, head, j8, base8, foff, h8, rowptr, col,
                            s_src, s_dst, bias, l5);
        *(uint4*)(&ALds[nl * 264 + l5 * 8]) = ov;
    }
    __syncthreads();

    // phase B: 16x256 GEMM vs W2t, wave w -> cols w*64..+63
    int c16 = lane & 15, lq = lane >> 4;
    int cw = wv * 64;
    f32x4 acc[4] = {};
    #pragma unroll
    for (int ks = 0; ks < 8; ks++) {
        half8v af = *(const half8v*)(&ALds[c16 * 264 + ks * 32 + lq * 8]);
        #pragma unroll
        for (int nn = 0; nn < 4; nn++) {
            half8v bg = *(const half8v*)(W2t + (size_t)(cw + nn * 16 + c16) * 256 + ks * 32 + lq * 8);
            acc[nn] = __builtin_amdgcn_mfma_f32_16x16x32_f16(af, bg, acc[nn], 0, 0, 0);
        }
    }
    // fp8 C write
    #pragma unroll
    for (int r = 0; r < 4; r++) {
        int row = blockIdx.x * 16 + lq * 4 + r;
        if (row < n) {
            int q01 = __builtin_amdgcn_cvt_pk_fp8_f32(acc[0][r], acc[1][r], 0, false);
            int q23 = __builtin_amdgcn_cvt_pk_fp8_f32(acc[2][r], acc[3][r], 0, false);
            size_t base = (size_t)row * 256 + cw + c16;
            C8[base]      = (unsigned char)(q01 & 0xff);
            C8[base + 16] = (unsigned char)((q01 >> 8) & 0xff);
            C8[base + 32] = (unsigned char)(q23 & 0xff);
            C8[base + 48] = (unsigned char)((q23 >> 8) & 0xff);
        }
    }
    // layer-2 scores (head = wv)
    {
        float avs[4], avd[4];
        #pragma unroll
        for (int nn = 0; nn < 4; nn++) {
            avs[nn] = a2s[wv * 64 + nn * 16 + c16];
            avd[nn] = a2d[wv * 64 + nn * 16 + c16];
        }
        #pragma unroll
        for (int r = 0; r < 4; r++) {
            float ps = 0.f, pd = 0.f;
            #pragma unroll
            for (int nn = 0; nn < 4; nn++) {
                ps += acc[nn][r] * avs[nn];
                pd += acc[nn][r] * avd[nn];
            }
            #pragma unroll
            for (int off = 1; off < 16; off <<= 1) {
                ps += __shfl_xor(ps, off);
                pd += __shfl_xor(pd, off);
            }
            if (c16 == 0) {
                int gnode = blockIdx.x * 16 + lq * 4 + r;
                if (gnode < n) {
                    s_src2[gnode * 4 + wv] = ps;
                    s_dst2[gnode * 4 + wv] = pd;
                }
            }
        }
    }
}

// ---------------- layer-2 aggregation + fused layer-3 GEMM (8 MFMA/block) ----------
__global__ __launch_bounds__(256) void k_agg2(
        const unsigned char* __restrict__ h8, const int* __restrict__ rowptr,
        const unsigned short* __restrict__ col,
        const float* __restrict__ s_src, const float* __restrict__ s_dst,
        const float* __restrict__ bias,
        const unsigned short* __restrict__ W3ht,   // [16][256] f16
        const float* __restrict__ a3s, const float* __restrict__ a3d,
        unsigned short* __restrict__ h3,
        float* __restrict__ s_src3, float* __restrict__ s_dst3, int n) {
    __shared__ unsigned short ALds[16 * 264];
    int tid = threadIdx.x;
    int lane = tid & 63, wv = tid >> 6;
    int half = lane >> 5, l5 = lane & 31;
    int nl = wv * 2 + half;
    int node = blockIdx.x * 8 + nl;
    for (int i = tid; i < (8 * 264) / 2; i += 256) ((unsigned*)&ALds[8 * 264])[i] = 0;

    int head = l5 >> 3;
    int j8 = l5 & 7;
    int base8 = lane & ~7;
    unsigned foff = (unsigned)(l5 * 8);
    uint4 ov = agg_core(node, n, head, j8, base8, foff, h8, rowptr, col, s_src, s_dst, bias, l5);
    *(uint4*)(&ALds[nl * 264 + l5 * 8]) = ov;
    __syncthreads();

    if (wv == 0) {
        int col16 = lane & 15, lq = lane >> 4;
        f32x4 acc3 = {0.f, 0.f, 0.f, 0.f};
        #pragma unroll
        for (int ks = 0; ks < 8; ks++) {
            half8v af = *(const half8v*)(&ALds[col16 * 264 + ks * 32 + lq * 8]);
            half8v bg = *(const half8v*)(W3ht + col16 * 256 + ks * 32 + lq * 8);
            acc3 = __builtin_amdgcn_mfma_f32_16x16x32_f16(af, bg, acc3, 0, 0, 0);
        }
        float a3sv = a3s[col16], a3dv = a3d[col16];
        #pragma unroll
        for (int r = 0; r < 4; r++) {
            int row = lq * 4 + r;
            int gnode = blockIdx.x * 8 + row;
            float v = acc3[r];
            float ps = v * a3sv, pd = v * a3dv;
            #pragma unroll
            for (int off = 1; off < 16; off <<= 1) {
                ps += __shfl_xor(ps, off);
                pd += __shfl_xor(pd, off);
            }
            if (row < 8 && gnode < n) {
                h3[(size_t)gnode * 16 + col16] = f2h(v);
                if (col16 == 0) { s_src3[gnode] = ps; s_dst3[gnode] = pd; }
            }
        }
    }
}

// ---------------- layer 3 aggregation + inline scores + bias + log_softmax ----------
__global__ void k_agg3(const unsigned short* __restrict__ h3, const int* __restrict__ rowptr,
                       const unsigned short* __restrict__ col,
                       const float* __restrict__ s_src, const float* __restrict__ s_dst,
                       const float* __restrict__ b3,
                       float* __restrict__ outp, int n) {
    int wave = (blockIdx.x * blockDim.x + threadIdx.x) >> 6;
    int lane = threadIdx.x & 63;
    if (wave >= n) return;
    int g = lane >> 4, c = lane & 15;
    int gbase = lane & ~15;
    int rs = rowptr[wave], re = rowptr[wave + 1];
    float sdn = s_dst[wave];

    float z = 0.f, acc = 0.f;
    if (g == 0) {
        float p = __expf(fminf(lrelu(s_src[wave] + sdn), 80.f));
        z += p;
        acc += p * h2f(h3[(size_t)wave * 16 + c]);
    }
    int i = rs + g;
    for (; i + 12 < re; i += 16) {
        int ss[4];
        #pragma unroll
        for (int j = 0; j < 4; j++) ss[j] = col[i + 4 * j];
        float q_own = s_src[ss[c & 3]];
        float v0 = h2f(h3[(size_t)ss[0] * 16 + c]), v1 = h2f(h3[(size_t)ss[1] * 16 + c]);
        float v2 = h2f(h3[(size_t)ss[2] * 16 + c]), v3 = h2f(h3[(size_t)ss[3] * 16 + c]);
        float p_own = __expf(fminf(lrelu(q_own + sdn), 80.f));
        float p0 = __shfl(p_own, gbase + 0);
        float p1 = __shfl(p_own, gbase + 1);
        float p2 = __shfl(p_own, gbase + 2);
        float p3 = __shfl(p_own, gbase + 3);
        z += (p0 + p1) + (p2 + p3);
        acc += p0 * v0 + p1 * v1 + p2 * v2 + p3 * v3;
    }
    for (; i < re; i += 4) {
        int s = col[i];
        float p = __expf(fminf(lrelu(s_src[s] + sdn), 80.f));
        z += p;
        acc += p * h2f(h3[(size_t)s * 16 + c]);
    }
    z += __shfl_xor(z, 16);  z += __shfl_xor(z, 32);
    acc += __shfl_xor(acc, 16); acc += __shfl_xor(acc, 32);
    if (lane < 16) {
        float v = acc / z + b3[c];
        float mm = v;
        #pragma unroll
        for (int off = 1; off < 16; off <<= 1) mm = fmaxf(mm, __shfl_xor(mm, off));
        float se = __expf(v - mm);
        #pragma unroll
        for (int off = 1; off < 16; off <<= 1) se += __shfl_xor(se, off);
        outp[(size_t)wave * 16 + c] = v - mm - logf(se);
    }
}

extern "C" void kernel_launch(void* const* d_in, const int* in_sizes, int n_in,
                              void* d_out, int out_size, void* d_ws, size_t ws_size,
                              hipStream_t stream) {
    const float* x      = (const float*)d_in[0];
    const int*   ei     = (const int*)d_in[1];
    const float* W1     = (const float*)d_in[2];
    const float* a1_src = (const float*)d_in[3];
    const float* a1_dst = (const float*)d_in[4];
    const float* b1     = (const float*)d_in[5];
    const float* W2     = (const float*)d_in[6];
    const float* a2_src = (const float*)d_in[7];
    const float* a2_dst = (const float*)d_in[8];
    const float* b2     = (const float*)d_in[9];
    const float* W3     = (const float*)d_in[10];
    const float* a3_src = (const float*)d_in[11];
    const float* a3_dst = (const float*)d_in[12];
    const float* b3     = (const float*)d_in[13];
    float* outp = (float*)d_out;

    const int N = N_NODES, E = N_EDGES;
    const int* src = ei;
    const int* dst = ei + E;

    char* ws = (char*)d_ws;
    size_t off = 0;
    auto alloc = [&](size_t bytes) {
        void* p = ws + off;
        off = (off + bytes + 255) & ~(size_t)255;
        return p;
    };
    int*   rowptr = (int*)alloc((N + 1) * sizeof(int));
    int*   counts = (int*)alloc(N * sizeof(int));
    unsigned short* col = (unsigned short*)alloc(E * sizeof(short));
    unsigned short* rank = (unsigned short*)alloc(E * sizeof(short));
    int*   incl   = (int*)alloc(N * sizeof(int));
    int*   bsums  = (int*)alloc(64 * sizeof(int));
    int*   boffs  = (int*)alloc(64 * sizeof(int));
    float* s_src  = (float*)alloc((size_t)N * HEADS * sizeof(float));
    float* s_dst  = (float*)alloc((size_t)N * HEADS * sizeof(float));
    float* s_src2 = (float*)alloc((size_t)N * HEADS * sizeof(float));
    float* s_dst2 = (float*)alloc((size_t)N * HEADS * sizeof(float));
    float* s_src3 = (float*)alloc((size_t)N * sizeof(float));
    float* s_dst3 = (float*)alloc((size_t)N * sizeof(float));
    unsigned short* W1t = (unsigned short*)alloc((size_t)256 * F_IN * sizeof(short));
    unsigned short* W2t = (unsigned short*)alloc((size_t)256 * 256 * sizeof(short));
    unsigned short* W3ht = (unsigned short*)alloc((size_t)16 * 256 * sizeof(short));
    unsigned char* hA8  = (unsigned char*)alloc((size_t)N * 256);   // layer-1 h, fp8
    unsigned char* hB8  = (unsigned char*)alloc((size_t)N * 256);   // layer-2 h, fp8
    unsigned short* h3  = (unsigned short*)alloc((size_t)N * 16 * sizeof(short));
    (void)ws_size;

    const int aggBlocks  = (N + 3) / 4;        // k_agg3: 1 node/wave
    const int agg2Blocks = (N + 7) / 8;        // k_agg2: 8 nodes/block
    const int fuseBlocks = (N + 15) / 16;      // k_fuse2: 16 nodes/block
    const int gemmBlocks = ((N + 127) / 128) * 2;
    const int scatBlocks = ((E + 1) / 2 + 255) / 256;

    // ---- prep: zero counts, W transposes + hist/ranks ----
    k_zero<<<(N / 4 + 255) / 256, 256, 0, stream>>>((int4*)counts, N / 4);
    k_prep<<<NB_WT1 + NB_WT2 + NB_WT3 + NB_HIST, 256, 0, stream>>>(W1, W1t, W2, W2t, W3, W3ht,
                                                                   dst, counts, rank);

    // ---- CSR scan ----
    const int nb = (N + 1023) / 1024;
    k_scan1<<<nb, 256, 0, stream>>>(counts, incl, bsums, N);
    k_scan2<<<1, 64, 0, stream>>>(bsums, boffs, nb, rowptr + N);
    k_scan3<<<(N + 255) / 256, 256, 0, stream>>>(incl, counts, boffs, rowptr, N);

    // ---- fused: layer-1 GEMM (f32 x -> fp8 hA8, scores s1) + atomic-free scatter ----
    k_b<<<gemmBlocks + scatBlocks, 256, 0, stream>>>(x, W1t, a1_src, a1_dst, hA8, s_src, s_dst,
                                                     N, F_IN, gemmBlocks,
                                                     src, dst, rowptr, rank, col, E);
    // ---- fused: layer-1 aggregation + layer-2 GEMM -> hB8 fp8 + scores s2 ----
    k_fuse2<<<fuseBlocks, 256, 0, stream>>>(hA8, rowptr, col, s_src, s_dst, b1,
                                            W2t, a2_src, a2_dst, hB8, s_src2, s_dst2, N);
    // ---- layer-2 aggregation + fused layer-3 GEMM -> h3 f16 + scores s3 ----
    k_agg2<<<agg2Blocks, 256, 0, stream>>>(hB8, rowptr, col, s_src2, s_dst2, b2,
                                           W3ht, a3_src, a3_dst, h3, s_src3, s_dst3, N);
    // ---- layer 3 aggregation + log_softmax ----
    k_agg3<<<aggBlocks, 256, 0, stream>>>(h3, rowptr, col, s_src3, s_dst3, b3, outp, N);
}

// Round 19
// 204.218 us; speedup vs baseline: 1.1834x; 1.1834x over previous
//
#include <hip/hip_runtime.h>
#include <hip/hip_bf16.h>
#include <math.h>

#define N_NODES 50000
#define N_EDGES 800000
#define F_IN    128
#define HID     64
#define HEADS   4
#define NCLS    16
#define NEG_SLOPE 0.2f

typedef __attribute__((ext_vector_type(8))) _Float16 half8v;
typedef __attribute__((ext_vector_type(4))) float f32x4;
typedef __attribute__((ext_vector_type(2))) float f32x2;

static __device__ __forceinline__ float lrelu(float x) {
    return x >= 0.f ? x : NEG_SLOPE * x;
}
static __device__ __forceinline__ unsigned short f2h(float f) {
    _Float16 h = (_Float16)f;
    return __builtin_bit_cast(unsigned short, h);
}
static __device__ __forceinline__ float h2f(unsigned short u) {
    return (float)__builtin_bit_cast(_Float16, u);
}

// ---------------- zero counts ----------------
__global__ void k_zero(int4* __restrict__ p, int n4) {
    int i = blockIdx.x * blockDim.x + threadIdx.x;
    if (i < n4) p[i] = int4{0, 0, 0, 0};
}

// ---------------- fused prep: W1t, W2t, W3ht, edge histogram + ranks ----------------
#define NB_WT1  128           // 128*256 / 256
#define NB_WT2  256           // 256*256 / 256
#define NB_WT3  16            // 256*16 / 256
#define NB_HIST 3125          // E / 256
__global__ void k_prep(const float* __restrict__ W1, unsigned short* __restrict__ W1t,
                       const float* __restrict__ W2, unsigned short* __restrict__ W2t,
                       const float* __restrict__ W3, unsigned short* __restrict__ W3ht,
                       const int* __restrict__ dst, int* __restrict__ counts,
                       unsigned short* __restrict__ rank) {
    int bid = blockIdx.x, tid = threadIdx.x;
    if (bid < NB_WT1) {
        int i = bid * 256 + tid;
        int k = i >> 8, c = i & 255;
        W1t[c * F_IN + k] = f2h(W1[i]);
    } else if (bid < NB_WT1 + NB_WT2) {
        int i = (bid - NB_WT1) * 256 + tid;
        int k = i >> 8, c = i & 255;
        W2t[c * 256 + k] = f2h(W2[i]);
    } else if (bid < NB_WT1 + NB_WT2 + NB_WT3) {
        int i = (bid - NB_WT1 - NB_WT2) * 256 + tid;
        int k = i >> 4, c = i & 15;        // W3 is [256][16]
        W3ht[c * 256 + k] = f2h(W3[i]);
    } else {
        int i = (bid - NB_WT1 - NB_WT2 - NB_WT3) * 256 + tid;
        if (i < N_EDGES) rank[i] = (unsigned short)atomicAdd(&counts[dst[i]], 1);
    }
}

// ---------------- CSR scan ----------------
__global__ __launch_bounds__(256) void k_scan1(const int* __restrict__ counts, int* __restrict__ incl,
                                               int* __restrict__ bsums, int n) {
    __shared__ int wsum[4];
    int blk = blockIdx.x, tid = threadIdx.x;
    int lane = tid & 63, w = tid >> 6;
    int i0 = blk * 1024 + tid * 4;
    int v[4];
    #pragma unroll
    for (int j = 0; j < 4; j++) v[j] = (i0 + j < n) ? counts[i0 + j] : 0;
    int t = v[0] + v[1] + v[2] + v[3];
    int x = t;
    #pragma unroll
    for (int d = 1; d < 64; d <<= 1) { int y = __shfl_up(x, d); if (lane >= d) x += y; }
    if (lane == 63) wsum[w] = x;
    __syncthreads();
    int woff = 0;
    #pragma unroll
    for (int ww = 0; ww < 4; ww++) woff += (ww < w) ? wsum[ww] : 0;
    int p = woff + x - t;
    #pragma unroll
    for (int j = 0; j < 4; j++) { p += v[j]; if (i0 + j < n) incl[i0 + j] = p; }
    if (tid == 255) bsums[blk] = woff + x;
}

__global__ void k_scan2(const int* __restrict__ bsums, int* __restrict__ boffs, int nb, int* rowptr_end) {
    int lane = threadIdx.x;
    int v = (lane < nb) ? bsums[lane] : 0;
    int x = v;
    #pragma unroll
    for (int d = 1; d < 64; d <<= 1) { int y = __shfl_up(x, d); if (lane >= d) x += y; }
    if (lane < nb) boffs[lane] = x - v;
    if (lane == 63) *rowptr_end = x;
}

__global__ void k_scan3(const int* __restrict__ incl, const int* __restrict__ counts,
                        const int* __restrict__ boffs, int* __restrict__ rowptr, int n) {
    int i = blockIdx.x * blockDim.x + threadIdx.x;
    if (i < n) rowptr[i] = boffs[i >> 10] + incl[i] - counts[i];
}

// ---------------- swizzle for MFMA LDS tiles ----------------
static __device__ __forceinline__ int swz(int r, int lc) {
    return r * 4 + (lc ^ (r & 3) ^ ((r >> 2) & 1));
}

// ---------------- GEMM body (f16 MFMA, 128x256, 4 waves) + fused scores ----------
template<int CONVA>
static __device__ __forceinline__ void gemm_body(
        int bid, const void* __restrict__ Av, const unsigned short* __restrict__ Bt,
        const float* __restrict__ asrc, const float* __restrict__ adst,
        unsigned char* __restrict__ C8, float* __restrict__ s_src, float* __restrict__ s_dst,
        int M, int K, unsigned short* Asm, unsigned short* Bsm) {
    int tid = threadIdx.x;
    int lane = tid & 63, wid = tid >> 6;
    int bx = bid & 1, by = bid >> 1;
    int row0 = by * 128, col0 = bx * 128;
    int wr = wid >> 1, wc = wid & 1;
    f32x4 acc[4][4] = {};

    for (int k0 = 0; k0 < K; k0 += 32) {
        __syncthreads();
        #pragma unroll
        for (int s = 0; s < 2; s++) {
            int c = tid + s * 256;
            int row = c >> 2, lc = c & 3;
            int gr = row0 + row; if (gr >= M) gr = 0;
            uint4 va;
            if (CONVA) {
                const float* Af = (const float*)Av + (size_t)gr * K + k0 + lc * 8;
                float4 fa = *(const float4*)Af;
                float4 fb = *(const float4*)(Af + 4);
                va.x = (unsigned)f2h(fa.x) | ((unsigned)f2h(fa.y) << 16);
                va.y = (unsigned)f2h(fa.z) | ((unsigned)f2h(fa.w) << 16);
                va.z = (unsigned)f2h(fb.x) | ((unsigned)f2h(fb.y) << 16);
                va.w = (unsigned)f2h(fb.z) | ((unsigned)f2h(fb.w) << 16);
            } else {
                va = *(const uint4*)((const unsigned short*)Av + (size_t)gr * K + k0 + lc * 8);
            }
            *(uint4*)(&Asm[swz(row, lc) * 8]) = va;
            uint4 vb = *(const uint4*)(Bt + (size_t)(col0 + row) * K + k0 + lc * 8);
            *(uint4*)(&Bsm[swz(row, lc) * 8]) = vb;
        }
        __syncthreads();
        half8v af[4], bg[4];
        int lq = lane >> 4;
        #pragma unroll
        for (int m = 0; m < 4; m++) {
            int r = wr * 64 + m * 16 + (lane & 15);
            af[m] = *(const half8v*)(&Asm[swz(r, lq) * 8]);
        }
        #pragma unroll
        for (int n = 0; n < 4; n++) {
            int r = wc * 64 + n * 16 + (lane & 15);
            bg[n] = *(const half8v*)(&Bsm[swz(r, lq) * 8]);
        }
        #pragma unroll
        for (int m = 0; m < 4; m++)
            #pragma unroll
            for (int n = 0; n < 4; n++)
                acc[m][n] = __builtin_amdgcn_mfma_f32_16x16x32_f16(af[m], bg[n], acc[m][n], 0, 0, 0);
    }

    #pragma unroll
    for (int m = 0; m < 4; m++) {
        #pragma unroll
        for (int r = 0; r < 4; r++) {
            int row = row0 + wr * 64 + m * 16 + (lane >> 4) * 4 + r;
            if (row < M) {
                int q01 = __builtin_amdgcn_cvt_pk_fp8_f32(acc[m][0][r], acc[m][1][r], 0, false);
                int q23 = __builtin_amdgcn_cvt_pk_fp8_f32(acc[m][2][r], acc[m][3][r], 0, false);
                size_t base = (size_t)row * 256 + col0 + wc * 64 + (lane & 15);
                C8[base]      = (unsigned char)(q01 & 0xff);
                C8[base + 16] = (unsigned char)((q01 >> 8) & 0xff);
                C8[base + 32] = (unsigned char)(q23 & 0xff);
                C8[base + 48] = (unsigned char)((q23 >> 8) & 0xff);
            }
        }
    }

    int c16 = lane & 15, lq = lane >> 4;
    int head = bx * 2 + wc;
    float avs[4], avd[4];
    #pragma unroll
    for (int nn = 0; nn < 4; nn++) {
        avs[nn] = asrc[head * 64 + nn * 16 + c16];
        avd[nn] = adst[head * 64 + nn * 16 + c16];
    }
    #pragma unroll
    for (int mm = 0; mm < 4; mm++) {
        #pragma unroll
        for (int r = 0; r < 4; r++) {
            float ps = 0.f, pd = 0.f;
            #pragma unroll
            for (int nn = 0; nn < 4; nn++) {
                ps += acc[mm][nn][r] * avs[nn];
                pd += acc[mm][nn][r] * avd[nn];
            }
            #pragma unroll
            for (int off = 1; off < 16; off <<= 1) {
                ps += __shfl_xor(ps, off);
                pd += __shfl_xor(pd, off);
            }
            if (c16 == 0) {
                int grow = row0 + wr * 64 + mm * 16 + lq * 4 + r;
                if (grow < M) {
                    s_src[grow * 4 + head] = ps;
                    s_dst[grow * 4 + head] = pd;
                }
            }
        }
    }
}

// standalone GEMM (layer 2, f16 A, fp8 C)
__global__ __launch_bounds__(256) void k_gemm_mfma(const unsigned short* __restrict__ A,
                                                   const unsigned short* __restrict__ Bt,
                                                   const float* __restrict__ asrc,
                                                   const float* __restrict__ adst,
                                                   unsigned char* __restrict__ C8,
                                                   float* __restrict__ s_src,
                                                   float* __restrict__ s_dst,
                                                   int M, int K) {
    __shared__ unsigned short Asm[128 * 32];
    __shared__ unsigned short Bsm[128 * 32];
    gemm_body<0>(blockIdx.x, A, Bt, asrc, adst, C8, s_src, s_dst, M, K, Asm, Bsm);
}

// fused: layer-1 GEMM (f32 A, fp8 C) + atomic-free CSR scatter (ushort col)
__global__ __launch_bounds__(256) void k_b(const float* __restrict__ A,
                                           const unsigned short* __restrict__ Bt,
                                           const float* __restrict__ asrc,
                                           const float* __restrict__ adst,
                                           unsigned char* __restrict__ C8,
                                           float* __restrict__ s_src,
                                           float* __restrict__ s_dst,
                                           int M, int K, int gemmBlocks,
                                           const int* __restrict__ src, const int* __restrict__ dst,
                                           const int* __restrict__ rowptr,
                                           const unsigned short* __restrict__ rank,
                                           unsigned short* __restrict__ col, int e) {
    __shared__ unsigned short Asm[128 * 32];
    __shared__ unsigned short Bsm[128 * 32];
    int bid = blockIdx.x;
    if (bid < gemmBlocks) {
        gemm_body<1>(bid, A, Bt, asrc, adst, C8, s_src, s_dst, M, K, Asm, Bsm);
    } else {
        int half = (e + 1) >> 1;
        int i = (bid - gemmBlocks) * 256 + (int)threadIdx.x;
        if (i < half) {
            int d = dst[i];
            col[rowptr[d] + rank[i]] = (unsigned short)src[i];
        }
        int j = i + half;
        if (j < e) {
            int d = dst[j];
            col[rowptr[d] + rank[j]] = (unsigned short)src[j];
        }
    }
}

// ---------------- per-edge accumulate macros (fp8 h, pk_fma) ----------------
#define PEDGE(SV, SD) __expf(fminf(lrelu((SV) + (SD)), 80.f))
#define ACC8(P, HV) { \
    f32x2 pbc = {(P), (P)}; \
    f32x2 v0 = __builtin_amdgcn_cvt_pk_f32_fp8((HV).x, false); \
    f32x2 v1 = __builtin_amdgcn_cvt_pk_f32_fp8((HV).x, true);  \
    f32x2 v2 = __builtin_amdgcn_cvt_pk_f32_fp8((HV).y, false); \
    f32x2 v3 = __builtin_amdgcn_cvt_pk_f32_fp8((HV).y, true);  \
    asm("v_pk_fma_f32 %0, %1, %2, %0" : "+v"(a01) : "v"(v0), "v"(pbc)); \
    asm("v_pk_fma_f32 %0, %1, %2, %0" : "+v"(a23) : "v"(v1), "v"(pbc)); \
    asm("v_pk_fma_f32 %0, %1, %2, %0" : "+v"(a45) : "v"(v2), "v"(pbc)); \
    asm("v_pk_fma_f32 %0, %1, %2, %0" : "+v"(a67) : "v"(v3), "v"(pbc)); \
    z += (P); }

// aggregation core: returns packed f16 ov for this half's node (zeros if node>=n)
static __device__ __forceinline__ uint4 agg_core(
        int node, int n, int head, int j8, int base8, unsigned foff,
        const unsigned char* __restrict__ h8, const int* __restrict__ rowptr,
        const unsigned short* __restrict__ col,
        const float* __restrict__ s_src, const float* __restrict__ s_dst,
        const float* __restrict__ bias, int l5) {
    uint4 ov = {0, 0, 0, 0};
    if (node >= n) return ov;
    int rs = rowptr[node], re = rowptr[node + 1];
    float sd = s_dst[node * 4 + head];
    float z = 0.f;
    f32x2 a01 = {0.f, 0.f}, a23 = {0.f, 0.f}, a45 = {0.f, 0.f}, a67 = {0.f, 0.f};
    {
        float pself = PEDGE(s_src[node * 4 + head], sd);
        uint2 own = *(const uint2*)(h8 + (((unsigned)node << 8) + foff));
        ACC8(pself, own);
    }
    int i = rs;
    for (; i + 7 < re; i += 8) {
        unsigned cc[8];
        #pragma unroll
        for (int j = 0; j < 8; j++) cc[j] = col[i + j];
        float s_own = s_src[cc[j8] * 4 + head];
        uint2 hv[8];
        #pragma unroll
        for (int j = 0; j < 8; j++)
            hv[j] = *(const uint2*)(h8 + ((cc[j] << 8) + foff));
        float p_own = PEDGE(s_own, sd);
        float pv[8];
        #pragma unroll
        for (int j = 0; j < 8; j++) pv[j] = __shfl(p_own, base8 + j);
        #pragma unroll
        for (int j = 0; j < 8; j++) { ACC8(pv[j], hv[j]); }
    }
    for (; i + 3 < re; i += 4) {
        unsigned cc[4];
        #pragma unroll
        for (int j = 0; j < 4; j++) cc[j] = col[i + j];
        float s_own = s_src[cc[j8 & 3] * 4 + head];
        uint2 hv[4];
        #pragma unroll
        for (int j = 0; j < 4; j++)
            hv[j] = *(const uint2*)(h8 + ((cc[j] << 8) + foff));
        float p_own = PEDGE(s_own, sd);
        float pv[4];
        #pragma unroll
        for (int j = 0; j < 4; j++) pv[j] = __shfl(p_own, base8 + j);
        #pragma unroll
        for (int j = 0; j < 4; j++) { ACC8(pv[j], hv[j]); }
    }
    for (; i < re; i++) {
        unsigned c0 = col[i];
        float s0 = s_src[c0 * 4 + head];
        uint2 h0 = *(const uint2*)(h8 + ((c0 << 8) + foff));
        float p0 = PEDGE(s0, sd);
        ACC8(p0, h0);
    }
    float inv = 1.f / z;
    int f0 = l5 * 8;
    float4 bv0 = *(const float4*)(bias + f0);
    float4 bv1 = *(const float4*)(bias + f0 + 4);
    float o[8];
    o[0] = a01.x * inv + bv0.x; o[1] = a01.y * inv + bv0.y;
    o[2] = a23.x * inv + bv0.z; o[3] = a23.y * inv + bv0.w;
    o[4] = a45.x * inv + bv1.x; o[5] = a45.y * inv + bv1.y;
    o[6] = a67.x * inv + bv1.z; o[7] = a67.y * inv + bv1.w;
    #pragma unroll
    for (int j = 0; j < 8; j++) o[j] = o[j] > 0.f ? o[j] : __expf(o[j]) - 1.f;
    unsigned* wd = (unsigned*)&ov;
    #pragma unroll
    for (int j = 0; j < 4; j++)
        wd[j] = (unsigned)f2h(o[2 * j]) | ((unsigned)f2h(o[2 * j + 1]) << 16);
    return ov;
}

// ---------------- layer-1 aggregation (fp8 h, 2 nodes/wave) -> f16 out ----------
__global__ void k_aggregate(const unsigned char* __restrict__ h8, const int* __restrict__ rowptr,
                            const unsigned short* __restrict__ col,
                            const float* __restrict__ s_src, const float* __restrict__ s_dst,
                            const float* __restrict__ bias,
                            unsigned short* __restrict__ out, int n) {
    int wave = (blockIdx.x * blockDim.x + threadIdx.x) >> 6;
    int lane = threadIdx.x & 63;
    int half = lane >> 5, l5 = lane & 31;
    int node = wave * 2 + half;
    if (node >= n) return;
    int head = l5 >> 3;
    int j8 = l5 & 7;
    int base8 = lane & ~7;
    unsigned foff = (unsigned)(l5 * 8);
    uint4 ov = agg_core(node, n, head, j8, base8, foff, h8, rowptr, col, s_src, s_dst, bias, l5);
    *(uint4*)(out + (size_t)node * 256 + l5 * 8) = ov;
}

// ---------------- layer-2 aggregation + fused layer-3 GEMM (8 MFMA/block) ----------
// 256 threads = 4 waves = 8 halves = 8 nodes/block. Epilogue: A-tile in LDS (16x264),
// wave 0 computes h3 = A @ W3 (16x16xK=256) + layer-3 scores.
__global__ __launch_bounds__(256) void k_agg2(
        const unsigned char* __restrict__ h8, const int* __restrict__ rowptr,
        const unsigned short* __restrict__ col,
        const float* __restrict__ s_src, const float* __restrict__ s_dst,
        const float* __restrict__ bias,
        const unsigned short* __restrict__ W3ht,   // [16][256] f16
        const float* __restrict__ a3s, const float* __restrict__ a3d,
        unsigned short* __restrict__ h3,
        float* __restrict__ s_src3, float* __restrict__ s_dst3, int n) {
    __shared__ unsigned short ALds[16 * 264];
    int tid = threadIdx.x;
    int lane = tid & 63, wv = tid >> 6;
    int half = lane >> 5, l5 = lane & 31;
    int nl = wv * 2 + half;
    int node = blockIdx.x * 8 + nl;
    // zero pad rows 8..15
    for (int i = tid; i < (8 * 264) / 2; i += 256) ((unsigned*)&ALds[8 * 264])[i] = 0;

    int head = l5 >> 3;
    int j8 = l5 & 7;
    int base8 = lane & ~7;
    unsigned foff = (unsigned)(l5 * 8);
    uint4 ov = agg_core(node, n, head, j8, base8, foff, h8, rowptr, col, s_src, s_dst, bias, l5);
    *(uint4*)(&ALds[nl * 264 + l5 * 8]) = ov;
    __syncthreads();

    if (wv == 0) {
        int col16 = lane & 15, lq = lane >> 4;
        f32x4 acc3 = {0.f, 0.f, 0.f, 0.f};
        #pragma unroll
        for (int ks = 0; ks < 8; ks++) {
            half8v af = *(const half8v*)(&ALds[col16 * 264 + ks * 32 + lq * 8]);
            half8v bg = *(const half8v*)(W3ht + col16 * 256 + ks * 32 + lq * 8);
            acc3 = __builtin_amdgcn_mfma_f32_16x16x32_f16(af, bg, acc3, 0, 0, 0);
        }
        float a3sv = a3s[col16], a3dv = a3d[col16];
        #pragma unroll
        for (int r = 0; r < 4; r++) {
            int row = lq * 4 + r;
            int gnode = blockIdx.x * 8 + row;
            float v = acc3[r];
            float ps = v * a3sv, pd = v * a3dv;
            #pragma unroll
            for (int off = 1; off < 16; off <<= 1) {
                ps += __shfl_xor(ps, off);
                pd += __shfl_xor(pd, off);
            }
            if (row < 8 && gnode < n) {
                h3[(size_t)gnode * 16 + col16] = f2h(v);
                if (col16 == 0) { s_src3[gnode] = ps; s_dst3[gnode] = pd; }
            }
        }
    }
}

// ---------------- layer 3 aggregation + inline scores + bias + log_softmax ----------
__global__ void k_agg3(const unsigned short* __restrict__ h3, const int* __restrict__ rowptr,
                       const unsigned short* __restrict__ col,
                       const float* __restrict__ s_src, const float* __restrict__ s_dst,
                       const float* __restrict__ b3,
                       float* __restrict__ outp, int n) {
    int wave = (blockIdx.x * blockDim.x + threadIdx.x) >> 6;
    int lane = threadIdx.x & 63;
    if (wave >= n) return;
    int g = lane >> 4, c = lane & 15;
    int gbase = lane & ~15;
    int rs = rowptr[wave], re = rowptr[wave + 1];
    float sdn = s_dst[wave];

    float z = 0.f, acc = 0.f;
    if (g == 0) {
        float p = __expf(fminf(lrelu(s_src[wave] + sdn), 80.f));
        z += p;
        acc += p * h2f(h3[(size_t)wave * 16 + c]);
    }
    int i = rs + g;
    for (; i + 12 < re; i += 16) {
        int ss[4];
        #pragma unroll
        for (int j = 0; j < 4; j++) ss[j] = col[i + 4 * j];
        float q_own = s_src[ss[c & 3]];
        float v0 = h2f(h3[(size_t)ss[0] * 16 + c]), v1 = h2f(h3[(size_t)ss[1] * 16 + c]);
        float v2 = h2f(h3[(size_t)ss[2] * 16 + c]), v3 = h2f(h3[(size_t)ss[3] * 16 + c]);
        float p_own = __expf(fminf(lrelu(q_own + sdn), 80.f));
        float p0 = __shfl(p_own, gbase + 0);
        float p1 = __shfl(p_own, gbase + 1);
        float p2 = __shfl(p_own, gbase + 2);
        float p3 = __shfl(p_own, gbase + 3);
        z += (p0 + p1) + (p2 + p3);
        acc += p0 * v0 + p1 * v1 + p2 * v2 + p3 * v3;
    }
    for (; i < re; i += 4) {
        int s = col[i];
        float p = __expf(fminf(lrelu(s_src[s] + sdn), 80.f));
        z += p;
        acc += p * h2f(h3[(size_t)s * 16 + c]);
    }
    z += __shfl_xor(z, 16);  z += __shfl_xor(z, 32);
    acc += __shfl_xor(acc, 16); acc += __shfl_xor(acc, 32);
    if (lane < 16) {
        float v = acc / z + b3[c];
        float mm = v;
        #pragma unroll
        for (int off = 1; off < 16; off <<= 1) mm = fmaxf(mm, __shfl_xor(mm, off));
        float se = __expf(v - mm);
        #pragma unroll
        for (int off = 1; off < 16; off <<= 1) se += __shfl_xor(se, off);
        outp[(size_t)wave * 16 + c] = v - mm - logf(se);
    }
}

extern "C" void kernel_launch(void* const* d_in, const int* in_sizes, int n_in,
                              void* d_out, int out_size, void* d_ws, size_t ws_size,
                              hipStream_t stream) {
    const float* x      = (const float*)d_in[0];
    const int*   ei     = (const int*)d_in[1];
    const float* W1     = (const float*)d_in[2];
    const float* a1_src = (const float*)d_in[3];
    const float* a1_dst = (const float*)d_in[4];
    const float* b1     = (const float*)d_in[5];
    const float* W2     = (const float*)d_in[6];
    const float* a2_src = (const float*)d_in[7];
    const float* a2_dst = (const float*)d_in[8];
    const float* b2     = (const float*)d_in[9];
    const float* W3     = (const float*)d_in[10];
    const float* a3_src = (const float*)d_in[11];
    const float* a3_dst = (const float*)d_in[12];
    const float* b3     = (const float*)d_in[13];
    float* outp = (float*)d_out;

    const int N = N_NODES, E = N_EDGES;
    const int* src = ei;
    const int* dst = ei + E;

    char* ws = (char*)d_ws;
    size_t off = 0;
    auto alloc = [&](size_t bytes) {
        void* p = ws + off;
        off = (off + bytes + 255) & ~(size_t)255;
        return p;
    };
    int*   rowptr = (int*)alloc((N + 1) * sizeof(int));
    int*   counts = (int*)alloc(N * sizeof(int));
    unsigned short* col = (unsigned short*)alloc(E * sizeof(short));
    unsigned short* rank = (unsigned short*)alloc(E * sizeof(short));
    int*   incl   = (int*)alloc(N * sizeof(int));
    int*   bsums  = (int*)alloc(64 * sizeof(int));
    int*   boffs  = (int*)alloc(64 * sizeof(int));
    float* s_src  = (float*)alloc((size_t)N * HEADS * sizeof(float));
    float* s_dst  = (float*)alloc((size_t)N * HEADS * sizeof(float));
    float* s_src3 = (float*)alloc((size_t)N * sizeof(float));
    float* s_dst3 = (float*)alloc((size_t)N * sizeof(float));
    unsigned short* W1t = (unsigned short*)alloc((size_t)256 * F_IN * sizeof(short));
    unsigned short* W2t = (unsigned short*)alloc((size_t)256 * 256 * sizeof(short));
    unsigned short* W3ht = (unsigned short*)alloc((size_t)16 * 256 * sizeof(short));
    unsigned char* hA8  = (unsigned char*)alloc((size_t)N * 256);   // fp8 h (per layer)
    unsigned short* hB  = (unsigned short*)alloc((size_t)N * 256 * sizeof(short));
    unsigned short* h3  = (unsigned short*)alloc((size_t)N * 16 * sizeof(short));
    (void)ws_size;

    const int aggBlocks  = (N + 3) / 4;        // k_agg3: 1 node/wave
    const int aggBlocks2 = (N + 7) / 8;        // k_aggregate / k_agg2: 8 nodes/block
    const int gemmBlocks = ((N + 127) / 128) * 2;
    const int scatBlocks = ((E + 1) / 2 + 255) / 256;

    // ---- prep: zero counts, W transposes + hist/ranks ----
    k_zero<<<(N / 4 + 255) / 256, 256, 0, stream>>>((int4*)counts, N / 4);
    k_prep<<<NB_WT1 + NB_WT2 + NB_WT3 + NB_HIST, 256, 0, stream>>>(W1, W1t, W2, W2t, W3, W3ht,
                                                                   dst, counts, rank);

    // ---- CSR scan ----
    const int nb = (N + 1023) / 1024;
    k_scan1<<<nb, 256, 0, stream>>>(counts, incl, bsums, N);
    k_scan2<<<1, 64, 0, stream>>>(bsums, boffs, nb, rowptr + N);
    k_scan3<<<(N + 255) / 256, 256, 0, stream>>>(incl, counts, boffs, rowptr, N);

    // ---- fused: layer-1 GEMM (f32 x -> fp8 hA8, scores s1) + atomic-free scatter ----
    k_b<<<gemmBlocks + scatBlocks, 256, 0, stream>>>(x, W1t, a1_src, a1_dst, hA8, s_src, s_dst,
                                                     N, F_IN, gemmBlocks,
                                                     src, dst, rowptr, rank, col, E);
    // ---- layer-1 aggregation -> hB f16 ----
    k_aggregate<<<aggBlocks2, 256, 0, stream>>>(hA8, rowptr, col, s_src, s_dst, b1, hB, N);
    // ---- layer 2 GEMM -> hA8 fp8 + scores s2 ----
    k_gemm_mfma<<<gemmBlocks, 256, 0, stream>>>(hB, W2t, a2_src, a2_dst, hA8, s_src, s_dst, N, 256);
    // ---- layer-2 aggregation + fused layer-3 GEMM -> h3 f16 + scores s3 ----
    k_agg2<<<aggBlocks2, 256, 0, stream>>>(hA8, rowptr, col, s_src, s_dst, b2,
                                           W3ht, a3_src, a3_dst, h3, s_src3, s_dst3, N);
    // ---- layer 3 aggregation + log_softmax ----
    k_agg3<<<aggBlocks, 256, 0, stream>>>(h3, rowptr, col, s_src3, s_dst3, b3, outp, N);
}